// Round 3
// baseline (287.557 us; speedup 1.0000x reference)
//
#include <hip/hip_runtime.h>

typedef unsigned short u16;
typedef __attribute__((ext_vector_type(8))) short bf16x8;
typedef __attribute__((ext_vector_type(4))) float f32x4;

__device__ inline u16 f2b(float f) {
    unsigned u;
    __builtin_memcpy(&u, &f, 4);
    unsigned r = u + 0x7FFF + ((u >> 16) & 1);  // RNE
    return (u16)(r >> 16);
}

__device__ inline bf16x8 pack8(const float* p) {
    union { u16 us[8]; bf16x8 v; } r;
#pragma unroll
    for (int i = 0; i < 8; i++) r.us[i] = f2b(p[i]);
    return r.v;
}

// ---------------------------------------------------------------------------
// GEMM: C[m][n] = sum_k A[m][k] * W[n][k] + bias[n]; W/bias are fp32 inputs,
// staged to bf16 LDS tiles with RNE.
// MODE 0: A = x (fp32). N=1536 fused over 3 weights; scatter bf16 Q,K ->
//         (s,h,tok,hd), V -> transposed (s,h,hd,tok).
// MODE 1: A = ctx (bf16 workspace). Plain row-major **fp32** output (d_out is
//         the reference's fp32 dtype -- round-2 lesson).
// Block: 256 thr = 4 waves, tile 128x128, BK=32, wave tile 64x64 (4x4 MFMA 16x16x32)
// ---------------------------------------------------------------------------
template <int MODE>
__global__ __launch_bounds__(256) void gemm_kernel(
    const void* __restrict__ Av, const float* __restrict__ W0, const float* __restrict__ W1,
    const float* __restrict__ W2, const float* __restrict__ B0, const float* __restrict__ B1,
    const float* __restrict__ B2, void* __restrict__ O0v, u16* __restrict__ O1, u16* __restrict__ O2) {
    const int K = 512;
    const int m0 = blockIdx.x * 128;
    const int n0 = blockIdx.y * 128;
    const int seg = (MODE == 0) ? (n0 >> 9) : 0;
    const int nl0 = (MODE == 0) ? (n0 & 511) : n0;
    const float* W = (seg == 0) ? W0 : (seg == 1) ? W1 : W2;
    const float* Bb = (seg == 0) ? B0 : (seg == 1) ? B1 : B2;
    u16* O = (seg == 0) ? (u16*)O0v : (seg == 1) ? O1 : O2;

    __shared__ __align__(16) u16 Al[128 * 32];
    __shared__ __align__(16) u16 Bl[128 * 32];

    const int tid = threadIdx.x;
    const int lane = tid & 63, wave = tid >> 6;
    const int quad = lane >> 4, col = lane & 15;
    const int wm = wave >> 1, wn = wave & 1;

    f32x4 acc[4][4];
#pragma unroll
    for (int i = 0; i < 4; i++)
#pragma unroll
        for (int j = 0; j < 4; j++) acc[i][j] = (f32x4){0.f, 0.f, 0.f, 0.f};

    for (int k0 = 0; k0 < K; k0 += 32) {
#pragma unroll
        for (int sh = 0; sh < 2; sh++) {
            int c = tid + sh * 256;  // 512 chunks of 8 elems per buffer
            int row = c >> 2, cc = (c & 3) * 8;
            if (MODE == 0) {
                const float* Af = (const float*)Av;
                float ab[8];
                *(float4*)&ab[0] = *(const float4*)&Af[(size_t)(m0 + row) * K + k0 + cc];
                *(float4*)&ab[4] = *(const float4*)&Af[(size_t)(m0 + row) * K + k0 + cc + 4];
                *(bf16x8*)&Al[row * 32 + cc] = pack8(ab);
            } else {
                const u16* Ab = (const u16*)Av;
                *(bf16x8*)&Al[row * 32 + cc] = *(const bf16x8*)&Ab[(size_t)(m0 + row) * K + k0 + cc];
            }
            float wb[8];
            *(float4*)&wb[0] = *(const float4*)&W[(size_t)(nl0 + row) * K + k0 + cc];
            *(float4*)&wb[4] = *(const float4*)&W[(size_t)(nl0 + row) * K + k0 + cc + 4];
            *(bf16x8*)&Bl[row * 32 + cc] = pack8(wb);
        }
        __syncthreads();
        bf16x8 af[4], bfr[4];
#pragma unroll
        for (int t = 0; t < 4; t++) {
            af[t] = *(const bf16x8*)&Al[(wm * 64 + t * 16 + col) * 32 + quad * 8];
            bfr[t] = *(const bf16x8*)&Bl[(wn * 64 + t * 16 + col) * 32 + quad * 8];
        }
#pragma unroll
        for (int i = 0; i < 4; i++)
#pragma unroll
            for (int j = 0; j < 4; j++)
                acc[i][j] = __builtin_amdgcn_mfma_f32_16x16x32_bf16(af[i], bfr[j], acc[i][j], 0, 0, 0);
        __syncthreads();
    }

    float bias[4];
#pragma unroll
    for (int j = 0; j < 4; j++) bias[j] = Bb[nl0 + wn * 64 + j * 16 + col];

#pragma unroll
    for (int i = 0; i < 4; i++) {
        const int mbase = m0 + wm * 64 + i * 16 + quad * 4;
#pragma unroll
        for (int j = 0; j < 4; j++) {
            const int nl = nl0 + wn * 64 + j * 16 + col;
            if (MODE == 1) {
                float* Of = (float*)O0v;  // fp32 final output
#pragma unroll
                for (int r = 0; r < 4; r++)
                    Of[(size_t)(mbase + r) * 512 + nl] = acc[i][j][r] + bias[j];
            } else {
                const int h = nl >> 6, hd = nl & 63;
                if (seg < 2) {
                    // Q/K layout: ((s*8+h)*1024 + tok)*64 + hd
#pragma unroll
                    for (int r = 0; r < 4; r++) {
                        int m = mbase + r;
                        int s = m >> 10, tok = m & 1023;
                        O[(size_t)((s * 8 + h) * 1024 + tok) * 64 + hd] = f2b(acc[i][j][r] + bias[j]);
                    }
                } else {
                    // V transposed: ((s*8+h)*64 + hd)*1024 + tok ; 4 tokens contiguous
                    int s = mbase >> 10, tok0 = mbase & 1023;
                    union { u16 us[4]; uint2 v; } pk;
#pragma unroll
                    for (int r = 0; r < 4; r++) pk.us[r] = f2b(acc[i][j][r] + bias[j]);
                    *(uint2*)&O[(size_t)((s * 8 + h) * 64 + hd) * 1024 + tok0] = pk.v;
                }
            }
        }
    }
}

// ---------------------------------------------------------------------------
// Attention, wave-private: each wave owns 64 q-rows and streams all 16 key
// tiles. relu-normalize: ctx = (sum relu(s)*v) / (sum relu(s) + eps).
// S^T = K*Q^T (C rows = keys) so P packs to per-wave LDS with 8B stores and
// the denominator reduces with two shfl_xor. P round-trips LDS into A-layout
// for P@V. No cross-wave sharing; single barrier before epilogue (den LDS).
// ---------------------------------------------------------------------------
__global__ __launch_bounds__(256) void attn_kernel(const u16* __restrict__ Q,
                                                   const u16* __restrict__ Kp,
                                                   const u16* __restrict__ Vt,
                                                   u16* __restrict__ Ctx) {
    constexpr int SP = 72;  // P row stride: 16B-aligned frag reads, non-pow2 banks
    __shared__ __align__(16) u16 pl[4][64 * SP];
    __shared__ float dl[4][64];

    const int s = blockIdx.z, h = blockIdx.y, qt = blockIdx.x;
    const u16* Qh = Q + (size_t)(s * 8 + h) * 1024 * 64;
    const u16* Kh = Kp + (size_t)(s * 8 + h) * 1024 * 64;
    const u16* Vh = Vt + (size_t)(s * 8 + h) * 64 * 1024;

    const int tid = threadIdx.x;
    const int lane = tid & 63, wave = tid >> 6;
    const int quad = lane >> 4, col = lane & 15;
    const int q0 = qt * 256 + wave * 64;

    // Q fragments (B-operand: lane holds Q[q=col][hd=quad*8+j]), loaded once
    bf16x8 qf[4][2];
#pragma unroll
    for (int nt = 0; nt < 4; nt++)
#pragma unroll
        for (int kk = 0; kk < 2; kk++)
            qf[nt][kk] = *(const bf16x8*)&Qh[(size_t)(q0 + nt * 16 + col) * 64 + kk * 32 + quad * 8];

    f32x4 cacc[4][4];
#pragma unroll
    for (int i = 0; i < 4; i++)
#pragma unroll
        for (int j = 0; j < 4; j++) cacc[i][j] = (f32x4){0.f, 0.f, 0.f, 0.f};
    float den[4] = {0.f, 0.f, 0.f, 0.f};

    for (int kt = 0; kt < 16; kt++) {
        const int k0 = kt * 64;
        f32x4 sacc[4][4];
#pragma unroll
        for (int i = 0; i < 4; i++)
#pragma unroll
            for (int j = 0; j < 4; j++) sacc[i][j] = (f32x4){0.f, 0.f, 0.f, 0.f};

#pragma unroll
        for (int kk = 0; kk < 2; kk++) {
            bf16x8 kf[4];
#pragma unroll
            for (int mt = 0; mt < 4; mt++)
                kf[mt] = *(const bf16x8*)&Kh[(size_t)(k0 + mt * 16 + col) * 64 + kk * 32 + quad * 8];
#pragma unroll
            for (int mt = 0; mt < 4; mt++)
#pragma unroll
                for (int nt = 0; nt < 4; nt++)
                    sacc[mt][nt] =
                        __builtin_amdgcn_mfma_f32_16x16x32_bf16(kf[mt], qf[nt][kk], sacc[mt][nt], 0, 0, 0);
        }

        // scale + relu, accumulate denominator (fp32, pre-rounding), pack P to LDS
#pragma unroll
        for (int nt = 0; nt < 4; nt++) {
            float dpart = 0.f;
#pragma unroll
            for (int mt = 0; mt < 4; mt++) {
                union { u16 us[4]; uint2 v; } pk;
#pragma unroll
                for (int r = 0; r < 4; r++) {
                    float p = sacc[mt][nt][r] * 0.125f;  // 1/sqrt(HD=64)
                    p = p > 0.f ? p : 0.f;
                    dpart += p;
                    pk.us[r] = f2b(p);
                }
                // S^T C-layout: row(key)=mt*16+quad*4+r, col(q)=nt*16+col -> P[q][key]
                *(uint2*)&pl[wave][(nt * 16 + col) * SP + mt * 16 + quad * 4] = pk.v;
            }
            dpart += __shfl_xor(dpart, 16);
            dpart += __shfl_xor(dpart, 32);  // all 4 quads now hold full 64-key sum
            den[nt] += dpart;
        }

        // P @ V: A = P (lane holds P[q=col][key=quad*8+j]), B = V (transposed layout)
#pragma unroll
        for (int kk = 0; kk < 2; kk++) {
            bf16x8 pf[4], vf[4];
#pragma unroll
            for (int mt = 0; mt < 4; mt++)
                pf[mt] = *(const bf16x8*)&pl[wave][(mt * 16 + col) * SP + kk * 32 + quad * 8];
#pragma unroll
            for (int nt = 0; nt < 4; nt++)
                vf[nt] = *(const bf16x8*)&Vh[(size_t)(nt * 16 + col) * 1024 + k0 + kk * 32 + quad * 8];
#pragma unroll
            for (int mt = 0; mt < 4; mt++)
#pragma unroll
                for (int nt = 0; nt < 4; nt++)
                    cacc[mt][nt] =
                        __builtin_amdgcn_mfma_f32_16x16x32_bf16(pf[mt], vf[nt], cacc[mt][nt], 0, 0, 0);
        }
    }

    // transpose den (indexed by q=nt*16+col) to row-indexed via LDS
    if (quad == 0)
#pragma unroll
        for (int nt = 0; nt < 4; nt++) dl[wave][nt * 16 + col] = den[nt];
    __syncthreads();

    // normalize + write ctx in (s, tok, h*64+hd) layout for the output GEMM
#pragma unroll
    for (int mt = 0; mt < 4; mt++) {
        float inv[4];
#pragma unroll
        for (int r = 0; r < 4; r++) inv[r] = 1.f / (dl[wave][mt * 16 + quad * 4 + r] + 1e-6f);
#pragma unroll
        for (int nt = 0; nt < 4; nt++) {
#pragma unroll
            for (int r = 0; r < 4; r++) {
                const size_t row = (size_t)(s * 1024 + q0 + mt * 16 + quad * 4 + r);
                Ctx[row * 512 + h * 64 + nt * 16 + col] = f2b(cacc[mt][nt][r] * inv[r]);
            }
        }
    }
}

extern "C" void kernel_launch(void* const* d_in, const int* in_sizes, int n_in, void* d_out,
                              int out_size, void* d_ws, size_t ws_size, hipStream_t stream) {
    const float* x = (const float*)d_in[0];
    const float* wq = (const float*)d_in[1];
    const float* bq = (const float*)d_in[2];
    const float* wk = (const float*)d_in[3];
    const float* bk = (const float*)d_in[4];
    const float* wv = (const float*)d_in[5];
    const float* bv = (const float*)d_in[6];
    const float* wo = (const float*)d_in[7];
    const float* bo = (const float*)d_in[8];

    const size_t E = 16384ull * 512ull;  // elems per bf16 intermediate (16 MiB each)
    u16* qw = (u16*)d_ws;
    u16* kw = qw + E;
    u16* vw = kw + E;
    u16* cw = vw + E;

    // QKV projection (fp32 in, bf16 out), fused N=3*512, head-layout scatter
    gemm_kernel<0><<<dim3(128, 12), 256, 0, stream>>>(x, wq, wk, wv, bq, bk, bv, qw, kw, vw);
    // relu-normalized attention (bf16 in/out, fp32 accum)
    attn_kernel<<<dim3(4, 8, 16), 256, 0, stream>>>(qw, kw, vw, cw);
    // output projection (bf16 ctx, fp32 wo/bo, fp32 out)
    gemm_kernel<1><<<dim3(128, 4), 256, 0, stream>>>(cw, wo, nullptr, nullptr, bo, nullptr, nullptr,
                                                     d_out, nullptr, nullptr);
}

// Round 4
// 230.767 us; speedup vs baseline: 1.2461x; 1.2461x over previous
//
#include <hip/hip_runtime.h>

typedef unsigned short u16;
typedef __attribute__((ext_vector_type(8))) short bf16x8;
typedef __attribute__((ext_vector_type(4))) float f32x4;

__device__ inline u16 f2b(float f) {
    unsigned u;
    __builtin_memcpy(&u, &f, 4);
    unsigned r = u + 0x7FFF + ((u >> 16) & 1);  // RNE
    return (u16)(r >> 16);
}

__device__ inline bf16x8 pack8(const float* p) {
    union { u16 us[8]; bf16x8 v; } r;
#pragma unroll
    for (int i = 0; i < 8; i++) r.us[i] = f2b(p[i]);
    return r.v;
}

// async global->LDS, 16B per lane. LDS dest must be wave-uniform base + lane*16.
__device__ inline void gload16(const void* g, void* l) {
    __builtin_amdgcn_global_load_lds((__attribute__((address_space(1))) void*)g,
                                     (__attribute__((address_space(3))) void*)l, 16, 0, 0);
}

// ---------------------------------------------------------------------------
// One-shot fp32 -> bf16 conversion: x (4096 blocks) then wq,wk,wv,wo (128 each)
// into contiguous wb[4*512*512]. Memory-bound, ~10 us.
// ---------------------------------------------------------------------------
__global__ __launch_bounds__(256) void conv_kernel(const float* __restrict__ x,
                                                   const float* __restrict__ wq,
                                                   const float* __restrict__ wk,
                                                   const float* __restrict__ wv,
                                                   const float* __restrict__ wo,
                                                   u16* __restrict__ xb, u16* __restrict__ wb) {
    const int bid = blockIdx.x;
    const float* src;
    u16* dst;
    size_t base;
    if (bid < 4096) {
        src = x; dst = xb; base = (size_t)bid * 2048;
    } else {
        const int wsel = (bid - 4096) >> 7;
        src = (wsel == 0) ? wq : (wsel == 1) ? wk : (wsel == 2) ? wv : wo;
        dst = wb + (size_t)wsel * 262144;
        base = (size_t)((bid - 4096) & 127) * 2048;
    }
    const size_t idx = base + (size_t)threadIdx.x * 8;
    float a[8];
    *(float4*)&a[0] = *(const float4*)&src[idx];
    *(float4*)&a[4] = *(const float4*)&src[idx + 4];
    *(bf16x8*)&dst[idx] = pack8(a);
}

// ---------------------------------------------------------------------------
// bf16 GEMM (m97-style): C[m][n] = sum_k A[m][k]*W[n][k] + bias[n].
// global_load_lds 16B staging, 128x128 tile, BK=32, 4 waves, 4x4 16x16x32 frags.
// MODE 0: N=1536 (q|k|v rows of wb); scatter Q*0.125,K -> (s,h,tok,hd),
//         V -> transposed (s,h,hd,tok). MODE 1: fp32 row-major out (d_out).
// ---------------------------------------------------------------------------
template <int MODE>
__global__ __launch_bounds__(256) void gemm_kernel(const u16* __restrict__ A,
                                                   const u16* __restrict__ W,
                                                   const float* __restrict__ B0,
                                                   const float* __restrict__ B1,
                                                   const float* __restrict__ B2,
                                                   void* __restrict__ O0v, u16* __restrict__ O1,
                                                   u16* __restrict__ O2) {
    const int m0 = blockIdx.x * 128;
    const int n0 = blockIdx.y * 128;  // global W row (0..1535 MODE0, 0..511 MODE1)
    const int seg = (MODE == 0) ? (n0 >> 9) : 0;
    const int nl0 = (MODE == 0) ? (n0 & 511) : n0;
    const float* Bb = (seg == 0) ? B0 : (seg == 1) ? B1 : B2;
    u16* O = (seg == 0) ? (u16*)O0v : (seg == 1) ? O1 : O2;

    __shared__ __align__(16) u16 Al[128 * 32];
    __shared__ __align__(16) u16 Bl[128 * 32];

    const int tid = threadIdx.x;
    const int lane = tid & 63, wave = tid >> 6;
    const int quad = lane >> 4, col = lane & 15;
    const int wm = wave >> 1, wn = wave & 1;

    f32x4 acc[4][4];
#pragma unroll
    for (int i = 0; i < 4; i++)
#pragma unroll
        for (int j = 0; j < 4; j++) acc[i][j] = (f32x4){0.f, 0.f, 0.f, 0.f};

    for (int k0 = 0; k0 < 512; k0 += 32) {
#pragma unroll
        for (int sh = 0; sh < 4; sh++) {
            const int c = tid + sh * 256;  // 0..511 -> A tile, 512..1023 -> W tile
            const int cl = c & 511;
            const int row = cl >> 2, cc = (cl & 3) * 8;
            if (c < 512)
                gload16(&A[(size_t)(m0 + row) * 512 + k0 + cc], &Al[cl * 8]);
            else
                gload16(&W[(size_t)(n0 + row) * 512 + k0 + cc], &Bl[cl * 8]);
        }
        __syncthreads();  // drains vmcnt (global_load_lds) per m97 structure
        bf16x8 af[4], bfr[4];
#pragma unroll
        for (int t = 0; t < 4; t++) {
            af[t] = *(const bf16x8*)&Al[(wm * 64 + t * 16 + col) * 32 + quad * 8];
            bfr[t] = *(const bf16x8*)&Bl[(wn * 64 + t * 16 + col) * 32 + quad * 8];
        }
#pragma unroll
        for (int i = 0; i < 4; i++)
#pragma unroll
            for (int j = 0; j < 4; j++)
                acc[i][j] = __builtin_amdgcn_mfma_f32_16x16x32_bf16(af[i], bfr[j], acc[i][j], 0, 0, 0);
        __syncthreads();
    }

    float bias[4];
#pragma unroll
    for (int j = 0; j < 4; j++) bias[j] = Bb[nl0 + wn * 64 + j * 16 + col];

#pragma unroll
    for (int i = 0; i < 4; i++) {
        const int mbase = m0 + wm * 64 + i * 16 + quad * 4;
#pragma unroll
        for (int j = 0; j < 4; j++) {
            const int nl = nl0 + wn * 64 + j * 16 + col;
            if (MODE == 1) {
                float* Of = (float*)O0v;  // fp32 final output
#pragma unroll
                for (int r = 0; r < 4; r++)
                    Of[(size_t)(mbase + r) * 512 + nl] = acc[i][j][r] + bias[j];
            } else {
                const int h = nl >> 6, hd = nl & 63;
                if (seg < 2) {
                    const float qs = (seg == 0) ? 0.125f : 1.f;  // pre-scale Q by 1/sqrt(64)
#pragma unroll
                    for (int r = 0; r < 4; r++) {
                        int m = mbase + r;
                        int s = m >> 10, tok = m & 1023;
                        O[(size_t)((s * 8 + h) * 1024 + tok) * 64 + hd] =
                            f2b((acc[i][j][r] + bias[j]) * qs);
                    }
                } else {
                    // V transposed: ((s*8+h)*64 + hd)*1024 + tok ; 4 tokens contiguous
                    int s = mbase >> 10, tok0 = mbase & 1023;
                    union { u16 us[4]; uint2 v; } pk;
#pragma unroll
                    for (int r = 0; r < 4; r++) pk.us[r] = f2b(acc[i][j][r] + bias[j]);
                    *(uint2*)&O[(size_t)((s * 8 + h) * 64 + hd) * 1024 + tok0] = pk.v;
                }
            }
        }
    }
}

// ---------------------------------------------------------------------------
// Attention, 1 wave per block (no barriers): wave owns 64 q-rows, streams all
// 16 key tiles. ctx = (sum relu(s)*v)/(sum relu(s)+eps); Q pre-scaled.
// S^T = K*Q^T so C rows = keys; P packed to LDS via v_add(0x8000)+v_perm
// (round-half-up bf16, 1.5 ops per 2 vals) and read back in A-layout for P@V.
// Grid 2048 blocks -> 8 waves/CU.
// ---------------------------------------------------------------------------
__global__ __launch_bounds__(64, 2) void attn_kernel(const u16* __restrict__ Q,
                                                     const u16* __restrict__ Kp,
                                                     const u16* __restrict__ Vt,
                                                     u16* __restrict__ Ctx) {
    constexpr int SP = 72;  // P row stride: 16B-aligned frag reads, non-pow2 banks
    __shared__ __align__(16) u16 pl[64 * SP];
    __shared__ float dl[64];

    const int s = blockIdx.z, h = blockIdx.y, qt = blockIdx.x;  // qt 0..15
    const u16* Qh = Q + (size_t)(s * 8 + h) * 65536;
    const u16* Kh = Kp + (size_t)(s * 8 + h) * 65536;
    const u16* Vh = Vt + (size_t)(s * 8 + h) * 65536;

    const int lane = threadIdx.x;
    const int quad = lane >> 4, col = lane & 15;
    const int q0 = qt * 64;

    // Q fragments (B-operand: lane holds Q[q=col][hd=quad*8+j]), loaded once
    bf16x8 qf[4][2];
#pragma unroll
    for (int nt = 0; nt < 4; nt++)
#pragma unroll
        for (int kk = 0; kk < 2; kk++)
            qf[nt][kk] = *(const bf16x8*)&Qh[(size_t)(q0 + nt * 16 + col) * 64 + kk * 32 + quad * 8];

    f32x4 cacc[4][4];
#pragma unroll
    for (int i = 0; i < 4; i++)
#pragma unroll
        for (int j = 0; j < 4; j++) cacc[i][j] = (f32x4){0.f, 0.f, 0.f, 0.f};
    float den[4] = {0.f, 0.f, 0.f, 0.f};

    for (int kt = 0; kt < 16; kt++) {
        const int k0 = kt * 64;

        // hoist V loads to iteration top: QK MFMAs + pack cover their latency
        bf16x8 vf[2][4];
#pragma unroll
        for (int kk = 0; kk < 2; kk++)
#pragma unroll
            for (int nt = 0; nt < 4; nt++)
                vf[kk][nt] =
                    *(const bf16x8*)&Vh[(size_t)(nt * 16 + col) * 1024 + k0 + kk * 32 + quad * 8];

        bf16x8 kf[2][4];
#pragma unroll
        for (int kk = 0; kk < 2; kk++)
#pragma unroll
            for (int mt = 0; mt < 4; mt++)
                kf[kk][mt] =
                    *(const bf16x8*)&Kh[(size_t)(k0 + mt * 16 + col) * 64 + kk * 32 + quad * 8];

        f32x4 sacc[4][4];
#pragma unroll
        for (int i = 0; i < 4; i++)
#pragma unroll
            for (int j = 0; j < 4; j++) sacc[i][j] = (f32x4){0.f, 0.f, 0.f, 0.f};
#pragma unroll
        for (int kk = 0; kk < 2; kk++)
#pragma unroll
            for (int mt = 0; mt < 4; mt++)
#pragma unroll
                for (int nt = 0; nt < 4; nt++)
                    sacc[mt][nt] =
                        __builtin_amdgcn_mfma_f32_16x16x32_bf16(kf[kk][mt], qf[nt][kk], sacc[mt][nt], 0, 0, 0);

        // relu + denominator + cheap bf16 pack (round-half-up + v_perm pair pack)
#pragma unroll
        for (int nt = 0; nt < 4; nt++) {
            float dpart = 0.f;
#pragma unroll
            for (int mt = 0; mt < 4; mt++) {
                float p0 = fmaxf(sacc[mt][nt][0], 0.f);
                float p1 = fmaxf(sacc[mt][nt][1], 0.f);
                float p2 = fmaxf(sacc[mt][nt][2], 0.f);
                float p3 = fmaxf(sacc[mt][nt][3], 0.f);
                dpart += p0; dpart += p1; dpart += p2; dpart += p3;
                unsigned u0 = __float_as_uint(p0) + 0x8000u;
                unsigned u1 = __float_as_uint(p1) + 0x8000u;
                unsigned u2 = __float_as_uint(p2) + 0x8000u;
                unsigned u3 = __float_as_uint(p3) + 0x8000u;
                uint2 pk;
                pk.x = __builtin_amdgcn_perm(u1, u0, 0x07060302);  // [u1.hi : u0.hi]
                pk.y = __builtin_amdgcn_perm(u3, u2, 0x07060302);
                // S^T C-layout: row(key)=mt*16+quad*4+r, col(q)=nt*16+col -> P[q][key]
                *(uint2*)&pl[(nt * 16 + col) * SP + mt * 16 + quad * 4] = pk;
            }
            dpart += __shfl_xor(dpart, 16);
            dpart += __shfl_xor(dpart, 32);  // all quads hold full 64-key sum
            den[nt] += dpart;
        }

        // P @ V: A = P (lane holds P[q=col][key=quad*8+j]), B = V (transposed)
#pragma unroll
        for (int kk = 0; kk < 2; kk++) {
            bf16x8 pf[4];
#pragma unroll
            for (int mt = 0; mt < 4; mt++)
                pf[mt] = *(const bf16x8*)&pl[(mt * 16 + col) * SP + kk * 32 + quad * 8];
#pragma unroll
            for (int mt = 0; mt < 4; mt++)
#pragma unroll
                for (int nt = 0; nt < 4; nt++)
                    cacc[mt][nt] =
                        __builtin_amdgcn_mfma_f32_16x16x32_bf16(pf[mt], vf[kk][nt], cacc[mt][nt], 0, 0, 0);
        }
    }

    // transpose den (indexed by q=nt*16+col) to row-indexed via wave-private LDS
    if (quad == 0)
#pragma unroll
        for (int nt = 0; nt < 4; nt++) dl[nt * 16 + col] = den[nt];
    // same-wave LDS ordering: no barrier needed (proven by pl round-trip)

    // normalize + write ctx in (s, tok, h*64+hd) layout for the output GEMM
#pragma unroll
    for (int mt = 0; mt < 4; mt++) {
        float inv[4];
#pragma unroll
        for (int r = 0; r < 4; r++) inv[r] = 1.f / (dl[mt * 16 + quad * 4 + r] + 1e-6f);
#pragma unroll
        for (int nt = 0; nt < 4; nt++) {
#pragma unroll
            for (int r = 0; r < 4; r++) {
                const size_t row = (size_t)(s * 1024 + q0 + mt * 16 + quad * 4 + r);
                Ctx[row * 512 + h * 64 + nt * 16 + col] = f2b(cacc[mt][nt][r] * inv[r]);
            }
        }
    }
}

extern "C" void kernel_launch(void* const* d_in, const int* in_sizes, int n_in, void* d_out,
                              int out_size, void* d_ws, size_t ws_size, hipStream_t stream) {
    const float* x = (const float*)d_in[0];
    const float* wq = (const float*)d_in[1];
    const float* bq = (const float*)d_in[2];
    const float* wk = (const float*)d_in[3];
    const float* bk = (const float*)d_in[4];
    const float* wv = (const float*)d_in[5];
    const float* bv = (const float*)d_in[6];
    const float* wo = (const float*)d_in[7];
    const float* bo = (const float*)d_in[8];

    const size_t E = 16384ull * 512ull;
    u16* xb = (u16*)d_ws;       // bf16 x; aliased as ctx after gemm0 consumes it
    u16* cw = xb;
    u16* wb = xb + E;           // bf16 wq|wk|wv|wo (4*262144)
    u16* qw = wb + 4 * 262144;
    u16* kw = qw + E;
    u16* vw = kw + E;

    // one-shot fp32->bf16 of x + weights
    conv_kernel<<<dim3(4096 + 512), 256, 0, stream>>>(x, wq, wk, wv, wo, xb, wb);
    // QKV projection (bf16 m97-style), head-layout scatter, Q pre-scaled
    gemm_kernel<0><<<dim3(128, 12), 256, 0, stream>>>(xb, wb, bq, bk, bv, qw, kw, vw);
    // relu-normalized attention, 1-wave blocks
    attn_kernel<<<dim3(16, 8, 16), 64, 0, stream>>>(qw, kw, vw, cw);
    // output projection -> fp32 d_out
    gemm_kernel<1><<<dim3(128, 4), 256, 0, stream>>>(cw, wb + 3 * 262144, bo, nullptr, nullptr,
                                                     d_out, nullptr, nullptr);
}